// Round 3
// baseline (54.097 us; speedup 1.0000x reference)
//
#include <hip/hip_runtime.h>

// attn [B=64, N=1024, N=1024] f32. Per (b, k=1..1022): unbiased std of the
// k-th super-diagonal scaled by (N-k)/5; mean over k then b -> scalar.
//
// Pass 1 (grid NB*RCH, 256 thr): rows of a block share i mod RCH (RCH%4==0),
// phase p=(-c) mod 4 (0->4) makes k=p+4t a 16B-aligned float4 window. Thread t
// owns 4 fixed k's for all its rows. Per-thread exact trip count
// M = ceil((N-k0-c)/RCH): interior rows load UNCONDITIONALLY (8-deep manual
// unroll -> 8 float4s in flight), only row M-1 masks lanes k0+1..3. Edge
// columns k=1..p-1 handled by threads 249..251 (wave 3, which has tiny M).
// Partials phase-relative at slot k-p; edges at 1024+k.
//
// Pass 2 (grid NB*4, 256 thr): reduce RCH chunk partials per (b,k), std
// formula, block reduce -> part[bid]; last arriving block (device-scope
// atomic counter, zeroed by pass 1) sums all 256 parts in fixed order ->
// scalar. Deterministic: single block, fixed-order tree.

#define NN 1024
#define NB 64
#define WSTRIDE 1032   // 1024 window slots + 3 edge slots + pad

template<int RCH>
__global__ __launch_bounds__(256) void diag_pass1(
    const float* __restrict__ attn, float* __restrict__ ws,
    unsigned int* __restrict__ counter) {
  const int b = blockIdx.x / RCH;
  const int c = blockIdx.x % RCH;
  const int t = threadIdx.x;
  if (blockIdx.x == 0 && t == 0)
    __hip_atomic_store(counter, 0u, __ATOMIC_RELAXED, __HIP_MEMORY_SCOPE_AGENT);

  int p = (4 - (c & 3)) & 3; if (p == 0) p = 4;   // k = p+4t is 16B-aligned
  const float* __restrict__ base = attn + ((size_t)b << 20);
  const int k0 = p + 4 * t;

  int M = (NN - k0 - c + RCH - 1) / RCH;          // rows with k0 valid
  if (M < 0) M = 0;

  const size_t rstride = (size_t)RCH * (NN + 1);
  const float* ptr = base + (size_t)c * (NN + 1) + k0;

  float s1x = 0.f, s1y = 0.f, s1z = 0.f, s1w = 0.f;
  float s2x = 0.f, s2y = 0.f, s2z = 0.f, s2w = 0.f;

  int m = 0;
  for (; m + 9 <= M; m += 8) {                    // 8 guaranteed-full rows
    float4 v0 = *reinterpret_cast<const float4*>(ptr + 0 * rstride);
    float4 v1 = *reinterpret_cast<const float4*>(ptr + 1 * rstride);
    float4 v2 = *reinterpret_cast<const float4*>(ptr + 2 * rstride);
    float4 v3 = *reinterpret_cast<const float4*>(ptr + 3 * rstride);
    float4 v4 = *reinterpret_cast<const float4*>(ptr + 4 * rstride);
    float4 v5 = *reinterpret_cast<const float4*>(ptr + 5 * rstride);
    float4 v6 = *reinterpret_cast<const float4*>(ptr + 6 * rstride);
    float4 v7 = *reinterpret_cast<const float4*>(ptr + 7 * rstride);
    ptr += 8 * rstride;
    s1x += v0.x; s2x += v0.x * v0.x; s1y += v0.y; s2y += v0.y * v0.y;
    s1z += v0.z; s2z += v0.z * v0.z; s1w += v0.w; s2w += v0.w * v0.w;
    s1x += v1.x; s2x += v1.x * v1.x; s1y += v1.y; s2y += v1.y * v1.y;
    s1z += v1.z; s2z += v1.z * v1.z; s1w += v1.w; s2w += v1.w * v1.w;
    s1x += v2.x; s2x += v2.x * v2.x; s1y += v2.y; s2y += v2.y * v2.y;
    s1z += v2.z; s2z += v2.z * v2.z; s1w += v2.w; s2w += v2.w * v2.w;
    s1x += v3.x; s2x += v3.x * v3.x; s1y += v3.y; s2y += v3.y * v3.y;
    s1z += v3.z; s2z += v3.z * v3.z; s1w += v3.w; s2w += v3.w * v3.w;
    s1x += v4.x; s2x += v4.x * v4.x; s1y += v4.y; s2y += v4.y * v4.y;
    s1z += v4.z; s2z += v4.z * v4.z; s1w += v4.w; s2w += v4.w * v4.w;
    s1x += v5.x; s2x += v5.x * v5.x; s1y += v5.y; s2y += v5.y * v5.y;
    s1z += v5.z; s2z += v5.z * v5.z; s1w += v5.w; s2w += v5.w * v5.w;
    s1x += v6.x; s2x += v6.x * v6.x; s1y += v6.y; s2y += v6.y * v6.y;
    s1z += v6.z; s2z += v6.z * v6.z; s1w += v6.w; s2w += v6.w * v6.w;
    s1x += v7.x; s2x += v7.x * v7.x; s1y += v7.y; s2y += v7.y * v7.y;
    s1z += v7.z; s2z += v7.z * v7.z; s1w += v7.w; s2w += v7.w * v7.w;
  }
  for (; m + 2 <= M; ++m) {                       // remaining full rows
    float4 v = *reinterpret_cast<const float4*>(ptr);
    ptr += rstride;
    s1x += v.x; s2x += v.x * v.x; s1y += v.y; s2y += v.y * v.y;
    s1z += v.z; s2z += v.z * v.z; s1w += v.w; s2w += v.w * v.w;
  }
  if (m < M) {                                    // last row: mask lanes 1..3
    const int lim = NN - (c + RCH * m);           // > k0 by construction
    float4 v = *reinterpret_cast<const float4*>(ptr);
    const float x0 = v.x;
    const float x1 = (k0 + 1 < lim) ? v.y : 0.f;
    const float x2 = (k0 + 2 < lim) ? v.z : 0.f;
    const float x3 = (k0 + 3 < lim) ? v.w : 0.f;
    s1x += x0; s2x += x0 * x0; s1y += x1; s2y += x1 * x1;
    s1z += x2; s2z += x2 * x2; s1w += x3; s2w += x3 * x3;
  }

  // Edge columns k = 1..p-1 (only when p > 1): threads 249..251.
  const int ek = t - 248;
  float e1 = 0.f, e2 = 0.f;
  if (ek >= 1 && ek < p) {
    const float* eptr = base + (size_t)c * (NN + 1) + ek;
    for (int i = c; i < NN - ek; i += RCH) {
      const float x = *eptr;
      e1 += x; e2 += x * x;
      eptr += rstride;
    }
  }

  float* __restrict__ w1 = ws + (size_t)blockIdx.x * (2 * WSTRIDE);
  float* __restrict__ w2 = w1 + WSTRIDE;
  *reinterpret_cast<float4*>(w1 + 4 * t) = make_float4(s1x, s1y, s1z, s1w);
  *reinterpret_cast<float4*>(w2 + 4 * t) = make_float4(s2x, s2y, s2z, s2w);
  if (ek >= 1 && ek < p) {
    w1[1024 + ek] = e1;
    w2[1024 + ek] = e2;
  }
}

template<int RCH>
__global__ __launch_bounds__(256) void diag_pass2(
    const float* __restrict__ ws, float* __restrict__ part,
    unsigned int* __restrict__ counter, float* __restrict__ out) {
  const int b  = blockIdx.x >> 2;
  const int kc = blockIdx.x & 3;
  const int t  = threadIdx.x;
  const int k  = kc * 256 + t;       // 0..1023; valid 1..1022

  float acc = 0.f;
  if (k >= 1 && k <= NN - 2) {
    float s1 = 0.f, s2 = 0.f;
    #pragma unroll
    for (int c = 0; c < RCH; ++c) {
      int p = (4 - (c & 3)) & 3; if (p == 0) p = 4;
      const float* __restrict__ w1 =
          ws + (size_t)(b * RCH + c) * (2 * WSTRIDE);
      const float* __restrict__ w2 = w1 + WSTRIDE;
      const int s = k - p;
      const int idx = (s >= 0) ? s : (1024 + k);   // window or edge slot
      s1 += w1[idx];
      s2 += w2[idx];
    }
    const float n = (float)(NN - k);
    const float mean = s1 / n;
    const float var = fmaxf(s2 - n * mean * mean, 0.f) / (n - 1.f);
    acc = sqrtf(var) * (n * 0.2f);   // std * (N-k)/5
  }

  __shared__ float red[256];
  red[t] = acc;
  __syncthreads();
  #pragma unroll
  for (int s = 128; s > 0; s >>= 1) {
    if (t < s) red[t] += red[t + s];
    __syncthreads();
  }

  __shared__ unsigned int amLast;
  if (t == 0) {
    __hip_atomic_store(&part[blockIdx.x], red[0],
                       __ATOMIC_RELEASE, __HIP_MEMORY_SCOPE_AGENT);
    const unsigned int old = __hip_atomic_fetch_add(
        counter, 1u, __ATOMIC_ACQ_REL, __HIP_MEMORY_SCOPE_AGENT);
    amLast = (old == gridDim.x - 1) ? 1u : 0u;
  }
  __syncthreads();
  if (amLast && t < 64) {            // one wave, fixed-order reduce
    float v = 0.f;
    #pragma unroll
    for (int j = 0; j < 4; ++j)
      v += __hip_atomic_load(&part[4 * t + j],
                             __ATOMIC_ACQUIRE, __HIP_MEMORY_SCOPE_AGENT);
    #pragma unroll
    for (int s = 32; s > 0; s >>= 1) v += __shfl_down(v, s);
    if (t == 0) out[0] = v * (1.0f / (1022.0f * 64.0f));
  }
}

template<int RCH>
static void launch_all(const float* attn, float* out, float* ws,
                       hipStream_t stream) {
  float* part = ws + (size_t)NB * RCH * 2 * WSTRIDE;          // 256 f32
  unsigned int* counter = (unsigned int*)(part + 256);        // 1 u32
  diag_pass1<RCH><<<NB * RCH, 256, 0, stream>>>(attn, ws, counter);
  diag_pass2<RCH><<<NB * 4, 256, 0, stream>>>(ws, part, counter, out);
}

extern "C" void kernel_launch(void* const* d_in, const int* in_sizes, int n_in,
                              void* d_out, int out_size, void* d_ws, size_t ws_size,
                              hipStream_t stream) {
  const float* attn = (const float*)d_in[0];
  float* out = (float*)d_out;
  float* ws = (float*)d_ws;

  const size_t need16 = ((size_t)NB * 16 * 2 * WSTRIDE + 256 + 1) * 4;
  const size_t need8  = ((size_t)NB * 8  * 2 * WSTRIDE + 256 + 1) * 4;

  if (ws_size >= need16)      launch_all<16>(attn, out, ws, stream);
  else if (ws_size >= need8)  launch_all<8>(attn, out, ws, stream);
  else                        launch_all<4>(attn, out, ws, stream);
}

// Round 4
// 47.154 us; speedup vs baseline: 1.1472x; 1.1472x over previous
//
#include <hip/hip_runtime.h>

// attn [B=64, N=1024, N=1024] f32. Per (b, k=1..1022): unbiased std of the
// k-th super-diagonal scaled by (N-k)/5; mean over k then b -> scalar.
//
// Pass 1 (grid NB*RCH, 256 thr): rows of a block share i mod RCH (RCH%4==0).
// Phase p=(-c) mod 4 (0->4) makes k=p+4t a 16B-aligned float4 window; thread
// t owns 4 fixed k's across all its rows (register accumulators, coalesced
// reads). Block-synchronized i-loop (R2 structure) with a WAVE-uniform trip
// count (lanes of wave w all have k0 >= p+256w, so the wave is idle once
// i >= NN-p-256w). Edge columns k=1..p-1: wave w==e handles column e, ONE row
// per lane + __shfl_xor reduce (the R3 serial edge loop was a ~15-20us
// straggler: 64 dependent-latency scalar loads on 3 lanes).
//
// Pass 2 (grid NB*4 = 256 blocks, 256 thr): reduce RCH chunk partials per
// (b,k), std formula, block reduce; last arriving block (device-scope atomic
// counter, reset by pass 1) does a fixed-order final sum -> scalar out.

#define NN 1024
#define NB 64
#define WSTRIDE 1032   // 1024 window slots + 3 edge slots + pad

template<int RCH>
__global__ __launch_bounds__(256) void diag_pass1(
    const float* __restrict__ attn, float* __restrict__ ws,
    unsigned int* __restrict__ counter) {
  const int b = blockIdx.x / RCH;
  const int c = blockIdx.x % RCH;
  const int t = threadIdx.x;
  if (blockIdx.x == 0 && t == 0)
    __hip_atomic_store(counter, 0u, __ATOMIC_RELAXED, __HIP_MEMORY_SCOPE_AGENT);

  int p = (4 - (c & 3)) & 3; if (p == 0) p = 4;   // k = p+4t is 16B-aligned
  const float* __restrict__ base = attn + ((size_t)b << 20);
  const int k0 = p + 4 * t;
  const int w  = t >> 6;                          // wave id 0..3

  // Wave-uniform trip count: wave w has an active lane iff i < NN-p-256w.
  const int Mw = (NN - p - 256 * w - c + RCH - 1) / RCH;

  const size_t rstride = (size_t)RCH * (NN + 1);
  const float* ptr = base + (size_t)c * (NN + 1) + k0;

  float s1x = 0.f, s1y = 0.f, s1z = 0.f, s1w = 0.f;
  float s2x = 0.f, s2y = 0.f, s2z = 0.f, s2w = 0.f;

  #pragma unroll 4
  for (int m = 0; m < Mw; ++m) {
    const int lim = NN - (c + RCH * m);           // element (i,k) valid iff k < lim
    if (k0 < lim) {
      const float4 v = *reinterpret_cast<const float4*>(ptr);
      const float x0 = v.x;                       // k0 < lim guaranteed here
      const float x1 = (k0 + 1 < lim) ? v.y : 0.f;
      const float x2 = (k0 + 2 < lim) ? v.z : 0.f;
      const float x3 = (k0 + 3 < lim) ? v.w : 0.f;
      s1x += x0; s2x += x0 * x0;
      s1y += x1; s2y += x1 * x1;
      s1z += x2; s2z += x2 * x2;
      s1w += x3; s2w += x3 * x3;
    }
    ptr += rstride;
  }

  float* __restrict__ w1 = ws + (size_t)blockIdx.x * (2 * WSTRIDE);
  float* __restrict__ w2 = w1 + WSTRIDE;
  *reinterpret_cast<float4*>(w1 + 4 * t) = make_float4(s1x, s1y, s1z, s1w);
  *reinterpret_cast<float4*>(w2 + 4 * t) = make_float4(s2x, s2y, s2z, s2w);

  // Edge columns k = 1..p-1: wave w handles column e=w, one row per lane.
  const int e = w;
  if (e >= 1 && e < p) {
    const int l = t & 63;
    float e1 = 0.f, e2 = 0.f;
    #pragma unroll
    for (int r = l; r < NN / RCH; r += 64) {
      const int i = c + RCH * r;
      if (i + e < NN) {                           // k=e valid iff i <= NN-1-e
        const float x = base[(size_t)i * (NN + 1) + e];
        e1 += x; e2 += x * x;
      }
    }
    #pragma unroll
    for (int s = 1; s < 64; s <<= 1) {
      e1 += __shfl_xor(e1, s);
      e2 += __shfl_xor(e2, s);
    }
    if (l == 0) {
      w1[1024 + e] = e1;
      w2[1024 + e] = e2;
    }
  }
}

template<int RCH>
__global__ __launch_bounds__(256) void diag_pass2(
    const float* __restrict__ ws, float* __restrict__ part,
    unsigned int* __restrict__ counter, float* __restrict__ out) {
  const int b  = blockIdx.x >> 2;
  const int kc = blockIdx.x & 3;
  const int t  = threadIdx.x;
  const int k  = kc * 256 + t;       // 0..1023; valid 1..1022

  float acc = 0.f;
  if (k >= 1 && k <= NN - 2) {
    float s1 = 0.f, s2 = 0.f;
    #pragma unroll
    for (int c = 0; c < RCH; ++c) {
      int p = (4 - (c & 3)) & 3; if (p == 0) p = 4;
      const float* __restrict__ w1 =
          ws + (size_t)(b * RCH + c) * (2 * WSTRIDE);
      const float* __restrict__ w2 = w1 + WSTRIDE;
      const int s = k - p;
      const int idx = (s >= 0) ? s : (1024 + k);   // window or edge slot
      s1 += w1[idx];
      s2 += w2[idx];
    }
    const float n = (float)(NN - k);
    const float mean = s1 / n;
    const float var = fmaxf(s2 - n * mean * mean, 0.f) / (n - 1.f);
    acc = sqrtf(var) * (n * 0.2f);   // std * (N-k)/5
  }

  __shared__ float red[256];
  red[t] = acc;
  __syncthreads();
  #pragma unroll
  for (int s = 128; s > 0; s >>= 1) {
    if (t < s) red[t] += red[t + s];
    __syncthreads();
  }

  __shared__ unsigned int amLast;
  if (t == 0) {
    __hip_atomic_store(&part[blockIdx.x], red[0],
                       __ATOMIC_RELEASE, __HIP_MEMORY_SCOPE_AGENT);
    const unsigned int old = __hip_atomic_fetch_add(
        counter, 1u, __ATOMIC_ACQ_REL, __HIP_MEMORY_SCOPE_AGENT);
    amLast = (old == gridDim.x - 1) ? 1u : 0u;
  }
  __syncthreads();
  if (amLast && t < 64) {            // one wave, fixed-order reduce
    float v = 0.f;
    #pragma unroll
    for (int j = 0; j < 4; ++j)
      v += __hip_atomic_load(&part[4 * t + j],
                             __ATOMIC_ACQUIRE, __HIP_MEMORY_SCOPE_AGENT);
    #pragma unroll
    for (int s = 32; s > 0; s >>= 1) v += __shfl_down(v, s);
    if (t == 0) out[0] = v * (1.0f / (1022.0f * 64.0f));
  }
}

template<int RCH>
static void launch_all(const float* attn, float* out, float* ws,
                       hipStream_t stream) {
  float* part = ws + (size_t)NB * RCH * 2 * WSTRIDE;          // 256 f32
  unsigned int* counter = (unsigned int*)(part + 256);        // 1 u32
  diag_pass1<RCH><<<NB * RCH, 256, 0, stream>>>(attn, ws, counter);
  diag_pass2<RCH><<<NB * 4, 256, 0, stream>>>(ws, part, counter, out);
}

extern "C" void kernel_launch(void* const* d_in, const int* in_sizes, int n_in,
                              void* d_out, int out_size, void* d_ws, size_t ws_size,
                              hipStream_t stream) {
  const float* attn = (const float*)d_in[0];
  float* out = (float*)d_out;
  float* ws = (float*)d_ws;

  const size_t need16 = ((size_t)NB * 16 * 2 * WSTRIDE + 256 + 1) * 4;
  const size_t need8  = ((size_t)NB * 8  * 2 * WSTRIDE + 256 + 1) * 4;

  if (ws_size >= need16)      launch_all<16>(attn, out, ws, stream);
  else if (ws_size >= need8)  launch_all<8>(attn, out, ws, stream);
  else                        launch_all<4>(attn, out, ws, stream);
}